// Round 10
// baseline (320.334 us; speedup 1.0000x reference)
//
#include <hip/hip_runtime.h>
#include <hip/hip_bf16.h>
#include <math.h>

#define N_MET 20000
#define N_RXN 50000
#define NEDGE 1000000
#define D 128
#define DH 64

typedef __attribute__((ext_vector_type(8))) short short8;   // 8 bf16 raw bits
typedef __attribute__((ext_vector_type(4))) float f32x4;

__device__ __forceinline__ unsigned short f2bf(float x){
    __hip_bfloat16 b = __float2bfloat16(x);
    return *reinterpret_cast<unsigned short*>(&b);
}
__device__ __forceinline__ float bf2f_lo(unsigned u){ return __uint_as_float(u << 16); }
__device__ __forceinline__ float bf2f_hi(unsigned u){ return __uint_as_float(u & 0xFFFF0000u); }

// ---- Kernel 1: weight converts + per-edge pack/count (int64 layout detected per-wave) ----
#define NB_WT ((D*D + 255)/256)        // 64
#define NB_W1 ((D*DH + 255)/256)       // 32
#define NB_EH ((NEDGE + 255)/256)      // 3907
__global__ __launch_bounds__(256) void prep_kernel(
    const float* __restrict__ Wt, const float* __restrict__ W1,
    const unsigned* __restrict__ he,
    unsigned short* __restrict__ WtT_bf, unsigned short* __restrict__ W1T_bf,
    int* __restrict__ count, unsigned* __restrict__ pack_he)
{
    int b = blockIdx.x;
    if (b < NB_WT){
        int i = b*256 + threadIdx.x;                  // WtT[c*D + k] = Wt[k*D + c]
        if (i < D*D){ int c = i >> 7, k = i & 127; WtT_bf[i] = f2bf(Wt[k*D + c]); }
    } else if (b < NB_WT + NB_W1){
        int i = (b - NB_WT)*256 + threadIdx.x;        // W1T[c*D + k] = W1[k*DH + c]
        if (i < DH*D){ int c = i >> 7, k = i & 127; W1T_bf[i] = f2bf(W1[k*DH + c]); }
    } else {
        // int64 layout iff the first 64 odd 32-bit words (high halves) are all zero
        unsigned long long mask = __ballot(he[2*(threadIdx.x & 63) + 1] != 0u);
        const int stride = (mask == 0ULL) ? 2 : 1;
        int e = (b - NB_WT - NB_W1)*256 + threadIdx.x;
        if (e < NEDGE){
            int m = (int)he[(size_t)e * stride];
            int r = (int)he[(size_t)(NEDGE + e) * stride];
            pack_he[e] = ((unsigned)r << 15) | (unsigned)m;
            atomicAdd(&count[r], 1);
        }
    }
}

// ---- Kernel 2: per-METABOLITE exp(gate) + transform table via MFMA (fp32 feats in) ----
// eg_m[m] = exp(gate(m)); T_bf[m][c] = bf16(relu(Wt^T f_m + bt)[c]).
// (No max-subtraction: softmax is shift-invariant; gate is O(1) so exp is safe —
//  validated rounds 9: absmax unchanged.)
#define NMTILE ((N_MET + 127) >> 7)   // 157
__global__ __launch_bounds__(512) void met_nn_kernel(
    const float* __restrict__ feats,
    const unsigned short* __restrict__ W1T_bf, const float* __restrict__ b1,
    const float* __restrict__ W2, const float* __restrict__ b2,
    const unsigned short* __restrict__ WtT_bf, const float* __restrict__ bt,
    float* __restrict__ eg_m, unsigned short* __restrict__ T_bf)
{
    __shared__ __align__(16) unsigned short Fs[128*136];
    __shared__ __align__(16) unsigned short W1s[64*136];
    __shared__ __align__(16) unsigned short Wts[128*136];

    const int tid = threadIdx.x;
    const int base = blockIdx.x * 128;

    for (int i = tid; i < 64*16; i += 512){
        int c = i >> 4, ch = i & 15;
        *(short8*)&W1s[c*136 + ch*8] = *(const short8*)&W1T_bf[c*128 + ch*8];
    }
    for (int i = tid; i < 128*16; i += 512){
        int c = i >> 4, ch = i & 15;
        *(short8*)&Wts[c*136 + ch*8] = *(const short8*)&WtT_bf[c*128 + ch*8];
    }
    {   // stage feats rows base..base+127 (fp32 -> bf16 in-register), 4 threads/row
        int row = tid >> 2, q = tid & 3;
        int m = base + row; if (m >= N_MET) m = N_MET - 1;
        const float4* src = (const float4*)(feats + (size_t)m * D);
        #pragma unroll
        for (int it = 0; it < 8; ++it){
            float4 v = src[q*8 + it];
            ushort4 o;
            o.x = f2bf(v.x); o.y = f2bf(v.y); o.z = f2bf(v.z); o.w = f2bf(v.w);
            *(ushort4*)&Fs[row*136 + (q*8 + it)*4] = o;
        }
    }
    __syncthreads();

    const int lane = tid & 63;
    const int wave = tid >> 6;
    const int erow = lane & 15;
    const int kgrp = lane >> 4;

    f32x4 acc1[4], acc2[8];
    #pragma unroll
    for (int cf = 0; cf < 4; ++cf) acc1[cf] = (f32x4){0.f,0.f,0.f,0.f};
    #pragma unroll
    for (int cf = 0; cf < 8; ++cf) acc2[cf] = (f32x4){0.f,0.f,0.f,0.f};

    #pragma unroll
    for (int ks = 0; ks < 4; ++ks){
        short8 a = *(const short8*)&Fs[(wave*16 + erow)*136 + ks*32 + kgrp*8];
        #pragma unroll
        for (int cf = 0; cf < 4; ++cf){
            short8 b = *(const short8*)&W1s[(cf*16 + erow)*136 + ks*32 + kgrp*8];
            acc1[cf] = __builtin_amdgcn_mfma_f32_16x16x32_bf16(a, b, acc1[cf], 0, 0, 0);
        }
        #pragma unroll
        for (int cf = 0; cf < 8; ++cf){
            short8 b = *(const short8*)&Wts[(cf*16 + erow)*136 + ks*32 + kgrp*8];
            acc2[cf] = __builtin_amdgcn_mfma_f32_16x16x32_bf16(a, b, acc2[cf], 0, 0, 0);
        }
    }

    // gate epilogue -> exp(gate)
    float p[4] = {0.f,0.f,0.f,0.f};
    #pragma unroll
    for (int cf = 0; cf < 4; ++cf){
        int c = cf*16 + erow;
        float b1c = b1[c], w2c = W2[c];
        #pragma unroll
        for (int r = 0; r < 4; ++r)
            p[r] += fmaxf(acc1[cf][r] + b1c, 0.f) * w2c;
    }
    #pragma unroll
    for (int off = 1; off < 16; off <<= 1){
        #pragma unroll
        for (int r = 0; r < 4; ++r) p[r] += __shfl_xor(p[r], off);
    }
    if (erow == 0){
        float b2v = b2[0];
        #pragma unroll
        for (int r = 0; r < 4; ++r){
            int m = base + wave*16 + kgrp*4 + r;
            if (m < N_MET) eg_m[m] = expf(p[r] + b2v);
        }
    }
    // T epilogue
    #pragma unroll
    for (int cf = 0; cf < 8; ++cf){
        int c = cf*16 + erow;
        float btc = bt[c];
        #pragma unroll
        for (int r = 0; r < 4; ++r){
            int m = base + wave*16 + kgrp*4 + r;
            if (m < N_MET)
                T_bf[(size_t)m*D + c] = f2bf(fmaxf(acc2[cf][r] + btc, 0.f));
        }
    }
}

// ---- Kernel 3: scan via wave shfl -> offsets, cursor ----
__global__ __launch_bounds__(1024) void scan_kernel(
    const int* __restrict__ count, int* __restrict__ offsets, int* __restrict__ cursor)
{
    __shared__ int wsum[16];
    __shared__ int sbase;
    const int tid = threadIdx.x, lane = tid & 63, wid = tid >> 6;
    if (tid == 0) sbase = 0;
    __syncthreads();
    for (int start = 0; start < N_RXN; start += 1024){
        int idx = start + tid;
        int v = (idx < N_RXN) ? count[idx] : 0;
        int x = v;
        #pragma unroll
        for (int off = 1; off < 64; off <<= 1){
            int t = __shfl_up(x, off);
            if (lane >= off) x += t;
        }
        if (lane == 63) wsum[wid] = x;
        __syncthreads();
        if (wid == 0){
            int s = (lane < 16) ? wsum[lane] : 0;
            #pragma unroll
            for (int off = 1; off < 16; off <<= 1){
                int t = __shfl_up(s, off);
                if (lane >= off) s += t;
            }
            if (lane < 16) wsum[lane] = s;
        }
        __syncthreads();
        int wbase = (wid == 0) ? 0 : wsum[wid-1];
        int excl = sbase + wbase + x - v;
        if (idx < N_RXN){ offsets[idx] = excl; cursor[idx] = excl; }
        __syncthreads();
        if (tid == 0) sbase += wsum[15];
        __syncthreads();
    }
    if (tid == 0) offsets[N_RXN] = sbase;
}

// ---- Kernel 4: counting-sort reorder (2B met scatter) + fused denom atomic ----
__global__ __launch_bounds__(256) void reorder_kernel(
    const unsigned* __restrict__ pack_he, const float* __restrict__ eg_m,
    int* __restrict__ cursor, unsigned short* __restrict__ sorted_met,
    float* __restrict__ denom)
{
    int e = blockIdx.x*256 + threadIdx.x;
    if (e >= NEDGE) return;
    unsigned pk = pack_he[e];
    int m = (int)(pk & 0x7FFFu);
    int r = (int)(pk >> 15);
    int pos = atomicAdd(&cursor[r], 1);
    sorted_met[pos] = (unsigned short)m;
    atomicAdd(&denom[r], eg_m[m]);
}

// ---- Kernel 5: one wave per reaction, single pass, LDS (m,a) broadcast ----
// lane owns cols (2*lane, 2*lane+1) via packed 4B T loads; exactly-once float2 store.
__global__ __launch_bounds__(256) void zsum_kernel(
    const int* __restrict__ offsets, const unsigned short* __restrict__ sorted_met,
    const float* __restrict__ eg_m, const float* __restrict__ denom,
    const unsigned* __restrict__ T2, float* __restrict__ Z)
{
    __shared__ uint2 ma[4][64];
    const int wv = threadIdx.x >> 6;
    const int r = blockIdx.x*4 + wv;
    if (r >= N_RXN) return;
    const int lane = threadIdx.x & 63;
    const int s = offsets[r], epos = offsets[r+1];

    float2 acc = {0.f, 0.f};
    if (epos > s){
        const float inv = 1.0f / denom[r];
        for (int c0 = s; c0 < epos; c0 += 64){
            int i = c0 + lane;
            if (i < epos){
                int m = sorted_met[i];
                float a = eg_m[m] * inv;
                ma[wv][lane] = make_uint2((unsigned)m, __float_as_uint(a));
            }
            int cnt = epos - c0; if (cnt > 64) cnt = 64;
            #pragma unroll 4
            for (int j = 0; j < cnt; ++j){
                uint2 v = ma[wv][j];                       // uniform ds_read_b64
                float aj = __uint_as_float(v.y);
                unsigned u = T2[(size_t)v.x*64 + lane];    // cols 2*lane, 2*lane+1
                acc.x += aj * bf2f_lo(u);
                acc.y += aj * bf2f_hi(u);
            }
        }
    }
    ((float2*)(Z + (size_t)r*D))[lane] = acc;   // covers empty rows too
}

extern "C" void kernel_launch(void* const* d_in, const int* in_sizes, int n_in,
                              void* d_out, int out_size, void* d_ws, size_t ws_size,
                              hipStream_t stream)
{
    const float* feats = (const float*)d_in[0];
    const int*   he    = (const int*)d_in[1];
    const float* W1    = (const float*)d_in[2];
    const float* b1    = (const float*)d_in[3];
    const float* W2    = (const float*)d_in[4];
    const float* b2    = (const float*)d_in[5];
    const float* Wt    = (const float*)d_in[6];
    const float* bt    = (const float*)d_in[7];
    float* Z = (float*)d_out;

    char* ws = (char*)d_ws;
    size_t off = 0;
    auto alloc = [&](size_t bytes)->char*{
        char* p = ws + off;
        off += (bytes + 255) & ~(size_t)255;
        return p;
    };
    unsigned short* WtT_bf    = (unsigned short*)alloc((size_t)D*D*2);
    unsigned short* W1T_bf    = (unsigned short*)alloc((size_t)D*DH*2);
    unsigned short* T_bf      = (unsigned short*)alloc((size_t)N_MET*D*2);  // 5.12 MB
    float*          eg_m      = (float*)         alloc((size_t)N_MET*4);
    char*           zero2     =                  alloc((size_t)N_RXN*8);    // count | denom
    int*            count     = (int*)            zero2;
    float*          denom     = (float*)         (zero2 + (size_t)N_RXN*4);
    int*            offsets   = (int*)           alloc((size_t)(N_RXN+1)*4);
    int*            cursor    = (int*)           alloc((size_t)N_RXN*4);
    unsigned short* sorted_met= (unsigned short*)alloc((size_t)NEDGE*2);    // 2 MB
    unsigned*       pack_he   = (unsigned*)      alloc((size_t)NEDGE*4);    // 4 MB

    hipMemsetAsync(zero2, 0, (size_t)N_RXN*8, stream);

    prep_kernel<<<NB_WT + NB_W1 + NB_EH, 256, 0, stream>>>(
        Wt, W1, (const unsigned*)he, WtT_bf, W1T_bf, count, pack_he);
    met_nn_kernel<<<NMTILE, 512, 0, stream>>>(feats, W1T_bf, b1, W2, b2,
                                              WtT_bf, bt, eg_m, T_bf);
    scan_kernel<<<1, 1024, 0, stream>>>(count, offsets, cursor);
    reorder_kernel<<<(NEDGE + 255)/256, 256, 0, stream>>>(pack_he, eg_m, cursor,
                                                          sorted_met, denom);
    zsum_kernel<<<(N_RXN + 3)/4, 256, 0, stream>>>(offsets, sorted_met, eg_m, denom,
                                                   (const unsigned*)T_bf, Z);
}

// Round 11
// 165.341 us; speedup vs baseline: 1.9374x; 1.9374x over previous
//
#include <hip/hip_runtime.h>
#include <hip/hip_bf16.h>
#include <math.h>

#define N_MET 20000
#define N_RXN 50000
#define NEDGE 1000000
#define D 128
#define DH 64
#define NBUCK ((N_RXN + 255) >> 8)          // 196 coarse buckets (rxn>>8)
#define CB_EDGES 4096
#define NB_CO ((NEDGE + CB_EDGES - 1) / CB_EDGES)   // 245

typedef __attribute__((ext_vector_type(8))) short short8;   // 8 bf16 raw bits
typedef __attribute__((ext_vector_type(4))) float f32x4;

__device__ __forceinline__ unsigned short f2bf(float x){
    __hip_bfloat16 b = __float2bfloat16(x);
    return *reinterpret_cast<unsigned short*>(&b);
}
__device__ __forceinline__ float bf2f_lo(unsigned u){ return __uint_as_float(u << 16); }
__device__ __forceinline__ float bf2f_hi(unsigned u){ return __uint_as_float(u & 0xFFFF0000u); }

// ---- Kernel 1: weight converts + per-edge pack + LDS-aggregated coarse histogram ----
#define NB_WT ((D*D + 255)/256)        // 64
#define NB_W1 ((D*DH + 255)/256)       // 32
__global__ __launch_bounds__(256) void prep_kernel(
    const float* __restrict__ Wt, const float* __restrict__ W1,
    const unsigned* __restrict__ he,
    unsigned short* __restrict__ WtT_bf, unsigned short* __restrict__ W1T_bf,
    int* __restrict__ ccount, unsigned* __restrict__ pack_he)
{
    int b = blockIdx.x;
    if (b < NB_WT){
        int i = b*256 + threadIdx.x;                  // WtT[c*D + k] = Wt[k*D + c]
        if (i < D*D){ int c = i >> 7, k = i & 127; WtT_bf[i] = f2bf(Wt[k*D + c]); }
        return;
    }
    if (b < NB_WT + NB_W1){
        int i = (b - NB_WT)*256 + threadIdx.x;        // W1T[c*D + k] = W1[k*DH + c]
        if (i < DH*D){ int c = i >> 7, k = i & 127; W1T_bf[i] = f2bf(W1[k*DH + c]); }
        return;
    }
    // edge blocks: 4096 edges each
    __shared__ int h[NBUCK];
    const int tid = threadIdx.x;
    for (int i = tid; i < NBUCK; i += 256) h[i] = 0;
    // int64 layout iff the first 64 odd 32-bit words (high halves) are all zero
    unsigned long long mask = __ballot(he[2*(tid & 63) + 1] != 0u);
    const int stride = (mask == 0ULL) ? 2 : 1;
    __syncthreads();
    const long base = (long)(b - NB_WT - NB_W1) * CB_EDGES;
    #pragma unroll
    for (int it = 0; it < 16; ++it){
        long e = base + it*256 + tid;
        if (e < NEDGE){
            int m = (int)he[(size_t)e * stride];
            int r = (int)he[(size_t)(NEDGE + e) * stride];
            pack_he[e] = ((unsigned)r << 15) | (unsigned)m;
            atomicAdd(&h[r >> 8], 1);
        }
    }
    __syncthreads();
    for (int i = tid; i < NBUCK; i += 256)
        if (h[i]) atomicAdd(&ccount[i], h[i]);
}

// ---- Kernel 2: per-METABOLITE exp(gate) + transform table via MFMA ----
#define NMTILE ((N_MET + 127) >> 7)   // 157
__global__ __launch_bounds__(512) void met_nn_kernel(
    const float* __restrict__ feats,
    const unsigned short* __restrict__ W1T_bf, const float* __restrict__ b1,
    const float* __restrict__ W2, const float* __restrict__ b2,
    const unsigned short* __restrict__ WtT_bf, const float* __restrict__ bt,
    float* __restrict__ eg_m, unsigned short* __restrict__ T_bf)
{
    __shared__ __align__(16) unsigned short Fs[128*136];
    __shared__ __align__(16) unsigned short W1s[64*136];
    __shared__ __align__(16) unsigned short Wts[128*136];

    const int tid = threadIdx.x;
    const int base = blockIdx.x * 128;

    for (int i = tid; i < 64*16; i += 512){
        int c = i >> 4, ch = i & 15;
        *(short8*)&W1s[c*136 + ch*8] = *(const short8*)&W1T_bf[c*128 + ch*8];
    }
    for (int i = tid; i < 128*16; i += 512){
        int c = i >> 4, ch = i & 15;
        *(short8*)&Wts[c*136 + ch*8] = *(const short8*)&WtT_bf[c*128 + ch*8];
    }
    {   // stage feats rows (fp32 -> bf16 in-register), 4 threads/row
        int row = tid >> 2, q = tid & 3;
        int m = base + row; if (m >= N_MET) m = N_MET - 1;
        const float4* src = (const float4*)(feats + (size_t)m * D);
        #pragma unroll
        for (int it = 0; it < 8; ++it){
            float4 v = src[q*8 + it];
            ushort4 o;
            o.x = f2bf(v.x); o.y = f2bf(v.y); o.z = f2bf(v.z); o.w = f2bf(v.w);
            *(ushort4*)&Fs[row*136 + (q*8 + it)*4] = o;
        }
    }
    __syncthreads();

    const int lane = tid & 63;
    const int wave = tid >> 6;
    const int erow = lane & 15;
    const int kgrp = lane >> 4;

    f32x4 acc1[4], acc2[8];
    #pragma unroll
    for (int cf = 0; cf < 4; ++cf) acc1[cf] = (f32x4){0.f,0.f,0.f,0.f};
    #pragma unroll
    for (int cf = 0; cf < 8; ++cf) acc2[cf] = (f32x4){0.f,0.f,0.f,0.f};

    #pragma unroll
    for (int ks = 0; ks < 4; ++ks){
        short8 a = *(const short8*)&Fs[(wave*16 + erow)*136 + ks*32 + kgrp*8];
        #pragma unroll
        for (int cf = 0; cf < 4; ++cf){
            short8 b = *(const short8*)&W1s[(cf*16 + erow)*136 + ks*32 + kgrp*8];
            acc1[cf] = __builtin_amdgcn_mfma_f32_16x16x32_bf16(a, b, acc1[cf], 0, 0, 0);
        }
        #pragma unroll
        for (int cf = 0; cf < 8; ++cf){
            short8 b = *(const short8*)&Wts[(cf*16 + erow)*136 + ks*32 + kgrp*8];
            acc2[cf] = __builtin_amdgcn_mfma_f32_16x16x32_bf16(a, b, acc2[cf], 0, 0, 0);
        }
    }

    float p[4] = {0.f,0.f,0.f,0.f};
    #pragma unroll
    for (int cf = 0; cf < 4; ++cf){
        int c = cf*16 + erow;
        float b1c = b1[c], w2c = W2[c];
        #pragma unroll
        for (int r = 0; r < 4; ++r)
            p[r] += fmaxf(acc1[cf][r] + b1c, 0.f) * w2c;
    }
    #pragma unroll
    for (int off = 1; off < 16; off <<= 1){
        #pragma unroll
        for (int r = 0; r < 4; ++r) p[r] += __shfl_xor(p[r], off);
    }
    if (erow == 0){
        float b2v = b2[0];
        #pragma unroll
        for (int r = 0; r < 4; ++r){
            int m = base + wave*16 + kgrp*4 + r;
            if (m < N_MET) eg_m[m] = expf(p[r] + b2v);
        }
    }
    #pragma unroll
    for (int cf = 0; cf < 8; ++cf){
        int c = cf*16 + erow;
        float btc = bt[c];
        #pragma unroll
        for (int r = 0; r < 4; ++r){
            int m = base + wave*16 + kgrp*4 + r;
            if (m < N_MET)
                T_bf[(size_t)m*D + c] = f2bf(fmaxf(acc2[cf][r] + btc, 0.f));
        }
    }
}

// ---- Kernel 3: scan of coarse counts -> cbase, ccursor (one block) ----
__global__ __launch_bounds__(256) void cscan_kernel(
    const int* __restrict__ ccount, int* __restrict__ cbase,
    int* __restrict__ ccursor, int* __restrict__ offsets)
{
    __shared__ int A[256];
    const int tid = threadIdx.x;
    int own = (tid < NBUCK) ? ccount[tid] : 0;
    A[tid] = own;
    __syncthreads();
    for (int off = 1; off < 256; off <<= 1){
        int t = (tid >= off) ? A[tid - off] : 0;
        __syncthreads();
        A[tid] += t;
        __syncthreads();
    }
    int excl = A[tid] - own;
    if (tid < NBUCK){ cbase[tid] = excl; ccursor[tid] = excl; }
    if (tid == NBUCK-1) cbase[NBUCK] = A[tid];
    if (tid == 0) offsets[N_RXN] = NEDGE;
}

// ---- Kernel 4: coarse scatter with LDS binning + per-bucket burst writes ----
__global__ __launch_bounds__(256) void coarse_kernel(
    const unsigned* __restrict__ pack_he, int* __restrict__ ccursor,
    unsigned* __restrict__ cpack)
{
    __shared__ int lh[NBUCK];
    __shared__ int lscan[NBUCK];
    __shared__ int lcur[NBUCK];
    __shared__ int ldelta[NBUCK];
    __shared__ int A[256];
    __shared__ unsigned lout[CB_EDGES];
    __shared__ unsigned short lbkt[CB_EDGES];

    const int tid = threadIdx.x;
    const long base = (long)blockIdx.x * CB_EDGES;
    const int n = (int)(((long)NEDGE - base) < CB_EDGES ? (NEDGE - base) : CB_EDGES);

    for (int i = tid; i < NBUCK; i += 256) lh[i] = 0;
    __syncthreads();

    unsigned pk[16];
    #pragma unroll
    for (int it = 0; it < 16; ++it){
        int idx = it*256 + tid;
        if (idx < n){
            pk[it] = pack_he[base + idx];
            atomicAdd(&lh[pk[it] >> 23], 1);
        }
    }
    __syncthreads();

    int own = (tid < NBUCK) ? lh[tid] : 0;
    A[tid] = own;
    __syncthreads();
    for (int off = 1; off < 256; off <<= 1){
        int t = (tid >= off) ? A[tid - off] : 0;
        __syncthreads();
        A[tid] += t;
        __syncthreads();
    }
    if (tid < NBUCK){ int e = A[tid] - own; lscan[tid] = e; lcur[tid] = e; }
    __syncthreads();

    #pragma unroll
    for (int it = 0; it < 16; ++it){
        int idx = it*256 + tid;
        if (idx < n){
            int bkt = pk[it] >> 23;
            int pos = atomicAdd(&lcur[bkt], 1);
            lout[pos] = pk[it];
            lbkt[pos] = (unsigned short)bkt;
        }
    }
    __syncthreads();

    if (tid < NBUCK && lh[tid] > 0){
        int g = atomicAdd(&ccursor[tid], lh[tid]);
        ldelta[tid] = g - lscan[tid];
    }
    __syncthreads();

    for (int i = tid; i < n; i += 256)
        cpack[ldelta[lbkt[i]] + i] = lout[i];
}

// ---- Kernel 5: per-bucket fine sort (writes offsets + sorted_met, no global atomics) ----
__global__ __launch_bounds__(256) void binsort_kernel(
    const unsigned* __restrict__ cpack, const int* __restrict__ cbase,
    int* __restrict__ offsets, unsigned short* __restrict__ sorted_met)
{
    __shared__ int fh[256];
    __shared__ int lcur[256];
    __shared__ int A[256];
    const int tid = threadIdx.x;
    const int b = blockIdx.x;
    const int cb = cbase[b], ce = cbase[b+1];
    const int n = ce - cb;

    fh[tid] = 0;
    __syncthreads();
    for (int i = tid; i < n; i += 256)
        atomicAdd(&fh[(cpack[cb + i] >> 15) & 255], 1);
    __syncthreads();

    int own = fh[tid];
    A[tid] = own;
    __syncthreads();
    for (int off = 1; off < 256; off <<= 1){
        int t = (tid >= off) ? A[tid - off] : 0;
        __syncthreads();
        A[tid] += t;
        __syncthreads();
    }
    int excl = A[tid] - own;
    lcur[tid] = excl;
    int r = b*256 + tid;
    if (r < N_RXN) offsets[r] = cb + excl;
    __syncthreads();

    for (int i = tid; i < n; i += 256){
        unsigned pk = cpack[cb + i];
        int f = (pk >> 15) & 255;
        int pos = atomicAdd(&lcur[f], 1);
        sorted_met[cb + pos] = (unsigned short)(pk & 0x7FFFu);
    }
}

// ---- Kernel 6: one wave per reaction: in-wave denom + LDS-broadcast weighted sum ----
__global__ __launch_bounds__(256) void zsum_kernel(
    const int* __restrict__ offsets, const unsigned short* __restrict__ sorted_met,
    const float* __restrict__ eg_m, const unsigned* __restrict__ T2,
    float* __restrict__ Z)
{
    __shared__ uint2 ma[4][64];
    const int wv = threadIdx.x >> 6;
    const int r = blockIdx.x*4 + wv;
    if (r >= N_RXN) return;
    const int lane = threadIdx.x & 63;
    const int s = offsets[r], e = offsets[r+1];
    const int n = e - s;

    float2 acc = {0.f, 0.f};
    if (n > 0){
        // pass 1: stage (m, eg) chunks; accumulate denom
        float dsum = 0.f;
        for (int c0 = s; c0 < e; c0 += 64){
            int i = c0 + lane;
            if (i < e){
                int m = sorted_met[i];
                float g = eg_m[m];
                ma[wv][lane] = make_uint2((unsigned)m, __float_as_uint(g));
                dsum += g;
            }
        }
        #pragma unroll
        for (int off = 1; off < 64; off <<= 1) dsum += __shfl_xor(dsum, off);
        const float inv = 1.0f / dsum;

        if (n <= 64){           // staged chunk still valid
            #pragma unroll 4
            for (int j = 0; j < n; ++j){
                uint2 v = ma[wv][j];
                float aj = __uint_as_float(v.y) * inv;
                unsigned u = T2[(size_t)v.x*64 + lane];
                acc.x += aj * bf2f_lo(u);
                acc.y += aj * bf2f_hi(u);
            }
        } else {                // rare: re-stage per chunk
            for (int c0 = s; c0 < e; c0 += 64){
                int i = c0 + lane;
                if (i < e){
                    int m = sorted_met[i];
                    ma[wv][lane] = make_uint2((unsigned)m, __float_as_uint(eg_m[m]));
                }
                int cnt = e - c0; if (cnt > 64) cnt = 64;
                #pragma unroll 4
                for (int j = 0; j < cnt; ++j){
                    uint2 v = ma[wv][j];
                    float aj = __uint_as_float(v.y) * inv;
                    unsigned u = T2[(size_t)v.x*64 + lane];
                    acc.x += aj * bf2f_lo(u);
                    acc.y += aj * bf2f_hi(u);
                }
            }
        }
    }
    ((float2*)(Z + (size_t)r*D))[lane] = acc;   // exactly-once; covers empty rows
}

extern "C" void kernel_launch(void* const* d_in, const int* in_sizes, int n_in,
                              void* d_out, int out_size, void* d_ws, size_t ws_size,
                              hipStream_t stream)
{
    const float* feats = (const float*)d_in[0];
    const int*   he    = (const int*)d_in[1];
    const float* W1    = (const float*)d_in[2];
    const float* b1    = (const float*)d_in[3];
    const float* W2    = (const float*)d_in[4];
    const float* b2    = (const float*)d_in[5];
    const float* Wt    = (const float*)d_in[6];
    const float* bt    = (const float*)d_in[7];
    float* Z = (float*)d_out;

    char* ws = (char*)d_ws;
    size_t off = 0;
    auto alloc = [&](size_t bytes)->char*{
        char* p = ws + off;
        off += (bytes + 255) & ~(size_t)255;
        return p;
    };
    unsigned short* WtT_bf    = (unsigned short*)alloc((size_t)D*D*2);
    unsigned short* W1T_bf    = (unsigned short*)alloc((size_t)D*DH*2);
    unsigned short* T_bf      = (unsigned short*)alloc((size_t)N_MET*D*2);  // 5.12 MB
    float*          eg_m      = (float*)         alloc((size_t)N_MET*4);
    int*            ccount    = (int*)           alloc((size_t)NBUCK*4);
    int*            cbase     = (int*)           alloc((size_t)(NBUCK+1)*4);
    int*            ccursor   = (int*)           alloc((size_t)NBUCK*4);
    int*            offsets   = (int*)           alloc((size_t)(N_RXN+1)*4);
    unsigned*       pack_he   = (unsigned*)      alloc((size_t)NEDGE*4);    // 4 MB
    unsigned*       cpack     = (unsigned*)      alloc((size_t)NEDGE*4);    // 4 MB
    unsigned short* sorted_met= (unsigned short*)alloc((size_t)NEDGE*2);    // 2 MB

    hipMemsetAsync(ccount, 0, (size_t)NBUCK*4, stream);

    prep_kernel<<<NB_WT + NB_W1 + NB_CO, 256, 0, stream>>>(
        Wt, W1, (const unsigned*)he, WtT_bf, W1T_bf, ccount, pack_he);
    met_nn_kernel<<<NMTILE, 512, 0, stream>>>(feats, W1T_bf, b1, W2, b2,
                                              WtT_bf, bt, eg_m, T_bf);
    cscan_kernel<<<1, 256, 0, stream>>>(ccount, cbase, ccursor, offsets);
    coarse_kernel<<<NB_CO, 256, 0, stream>>>(pack_he, ccursor, cpack);
    binsort_kernel<<<NBUCK, 256, 0, stream>>>(cpack, cbase, offsets, sorted_met);
    zsum_kernel<<<(N_RXN + 3)/4, 256, 0, stream>>>(offsets, sorted_met, eg_m,
                                                   (const unsigned*)T_bf, Z);
}